// Round 11
// baseline (291.864 us; speedup 1.0000x reference)
//
#include <hip/hip_runtime.h>
#include <stdint.h>

// WASLL R15: commit to the direct-gather path the R14 fallback accidentally
// benchmarked. R14's guard bug (NP % 16384 != 0) routed every iteration to
// the naive per-net gather -- which ran at 158us/kernel vs the champion
// pipeline's 270us TOTAL. Mechanism: pos (64MB) fits the 256MB Infinity
// Cache; the random pin reads are MSHR/latency-bound at ~3.2TB/s sector
// traffic (8M x 64B / 158us), matching the ~32K-outstanding x 64B / ~600ns
// queue model -- already at the memory-system ceiling, NOT an HBM disaster.
// The 3-pass sort solved a problem L3 already solves. R15 minimizes the path:
//   - hipMemsetAsync(out) replaces the 1-block zero_out kernel (prime
//     suspect in the 132us path overhead); 2 dispatches total.
//   - gather tuned: 512t blocks, 2 nets/thread (8 pos loads in flight,
//     VGPR ~48, no remat risk), per-dim guards skip inactive-dim exp work,
//     wave shfl + LDS reduce, one atomic per block.
// Falsifier: total >= 260 -> path overhead is harness-structural -> revert
// to the R12 pipeline (269.7us) next round.

#define GTHR 512

__device__ __forceinline__ float wa4(float a, float b, float c, float d, float ig) {
    float ea = __expf(a * ig), eb = __expf(b * ig);
    float ec = __expf(c * ig), ed = __expf(d * ig);
    float na = __expf(-a * ig), nb = __expf(-b * ig);
    float nc = __expf(-c * ig), nd = __expf(-d * ig);
    float s_ep  = ea + eb + ec + ed;
    float s_xep = a * ea + b * eb + c * ec + d * ed;
    float s_en  = na + nb + nc + nd;
    float s_xen = a * na + b * nb + c * nc + d * nd;
    return s_xep / s_ep - s_xen / s_en;
}

// ---------------- tuned direct gather: one pass, 2 nets/thread ----------------
__global__ __launch_bounds__(GTHR) void wasll_gather(
    const float2* __restrict__ pos, const int4* __restrict__ fnp4,
    const float* __restrict__ wts, const float* __restrict__ ig_p,
    const int* __restrict__ slrx_p, const int* __restrict__ slry_p,
    float* __restrict__ out, int N)
{
    const float ig = ig_p[0];
    const bool dx = slrx_p[0] > 1, dy = slry_p[0] > 1;

    const int n0 = blockIdx.x * (2 * GTHR) + threadIdx.x;   // coalesced pair
    const int n1 = n0 + GTHR;

    // issue both index loads, then all 8 pos loads (in flight together)
    int4 i0 = make_int4(0, 0, 0, 0), i1 = make_int4(0, 0, 0, 0);
    if (n0 < N) i0 = fnp4[n0];
    if (n1 < N) i1 = fnp4[n1];
    float2 a0 = pos[i0.x], a1 = pos[i0.y], a2 = pos[i0.z], a3 = pos[i0.w];
    float2 b0 = pos[i1.x], b1 = pos[i1.y], b2 = pos[i1.z], b3 = pos[i1.w];
    const float w0 = (n0 < N) ? wts[n0] : 0.0f;
    const float w1 = (n1 < N) ? wts[n1] : 0.0f;

    float s0 = 0.0f, s1 = 0.0f;
    if (dy) {                                   // bench path: y only
        s0 += wa4(a0.y, a1.y, a2.y, a3.y, ig);
        s1 += wa4(b0.y, b1.y, b2.y, b3.y, ig);
    }
    if (dx) {
        s0 += wa4(a0.x, a1.x, a2.x, a3.x, ig);
        s1 += wa4(b0.x, b1.x, b2.x, b3.x, ig);
    }
    float val = w0 * s0 + w1 * s1;

    #pragma unroll
    for (int off = 32; off > 0; off >>= 1) val += __shfl_down(val, off, 64);
    __shared__ float smem[GTHR / 64];
    if ((threadIdx.x & 63) == 0) smem[threadIdx.x >> 6] = val;
    __syncthreads();
    if (threadIdx.x == 0) {
        float s = 0.0f;
        #pragma unroll
        for (int w = 0; w < GTHR / 64; ++w) s += smem[w];
        atomicAdd(out, s);
    }
}

// ---------------- fallback: proven R1 gather kernel ----------------
__global__ __launch_bounds__(256) void wasll_fallback(
    const float2* __restrict__ pos, const int4* __restrict__ fnp4,
    const float* __restrict__ net_weights, const float* __restrict__ inv_gamma_p,
    const int* __restrict__ slrx_p, const int* __restrict__ slry_p,
    float* __restrict__ out, int num_nets)
{
    const float ig = inv_gamma_p[0];
    const float dx = (slrx_p[0] > 1) ? 1.0f : 0.0f;
    const float dy = (slry_p[0] > 1) ? 1.0f : 0.0f;
    int net = blockIdx.x * blockDim.x + threadIdx.x;
    float val = 0.0f;
    if (net < num_nets) {
        int4 idx = fnp4[net];
        float2 p0 = pos[idx.x], p1 = pos[idx.y], p2 = pos[idx.z], p3 = pos[idx.w];
        val = net_weights[net] * (dx * wa4(p0.x, p1.x, p2.x, p3.x, ig)
                                + dy * wa4(p0.y, p1.y, p2.y, p3.y, ig));
    }
    #pragma unroll
    for (int off = 32; off > 0; off >>= 1) val += __shfl_down(val, off, 64);
    __shared__ float smem[4];
    if ((threadIdx.x & 63) == 0) smem[threadIdx.x >> 6] = val;
    __syncthreads();
    if (threadIdx.x == 0)
        atomicAdd(out, smem[0] + smem[1] + smem[2] + smem[3]);
}

extern "C" void kernel_launch(void* const* d_in, const int* in_sizes, int n_in,
                              void* d_out, int out_size, void* d_ws, size_t ws_size,
                              hipStream_t stream) {
    const float* posf        = (const float*)d_in[0];
    const int*   fnp         = (const int*)d_in[1];
    const float* net_weights = (const float*)d_in[4];
    const float* inv_gamma   = (const float*)d_in[7];
    const int*   slrx        = (const int*)d_in[8];
    const int*   slry        = (const int*)d_in[9];
    float*       out         = (float*)d_out;
    const int    N  = in_sizes[4];
    const int    NP = in_sizes[1];

    // out[0] = 0 without a 1-block kernel dispatch
    hipMemsetAsync(out, 0, sizeof(float), stream);

    if (NP == 4 * N && N > 0) {
        const int grid = (N + 2 * GTHR - 1) / (2 * GTHR);   // 2 nets/thread
        hipLaunchKernelGGL(wasll_gather, dim3(grid), dim3(GTHR), 0, stream,
                           (const float2*)posf, (const int4*)fnp, net_weights,
                           inv_gamma, slrx, slry, out, N);
    } else {
        const int block = 256, grid = (N + block - 1) / block;
        hipLaunchKernelGGL(wasll_fallback, dim3(grid), dim3(block), 0, stream,
                           (const float2*)posf, (const int4*)fnp, net_weights,
                           inv_gamma, slrx, slry, out, N);
    }
}